// Round 4
// baseline (399.332 us; speedup 1.0000x reference)
//
#include <hip/hip_runtime.h>

// H=W=1024, T=16, 20 iterations.
//
// R9 = R8 + XCD-aware block swizzle (isolated change).
//
// Intermediates live in two VERTICAL-PAIR buffers:
//   buf2[r][c] = ( pad[r-1][c-1], pad[r][c-1] )   (float2, 8 B)
// where pad[y][x] is the zero-bordered padded canvas (pixel (h,w) at
// pad[h+1][w+1]). The 4 bilinear corners of a sample live in TWO ADJACENT f2
// elements -> ONE 16B dwordx4 gather per (pixel, transform). Guards/gutters
// are memset-zero once and never written, so clamped OOB samples read exact
// 0.0 (zeros padding exact, no per-lane cmp/cndmask).
//
// XCD swizzle: MI355X has 8 XCDs, round-robin blockIdx dispatch. tile =
// (lin&7)*512 + (lin>>3) gives each XCD a contiguous 512-tile chunk (a
// 128-row destination band). Per transform-phase, an XCD's L2 working set is
// that band's source bbox (~1.8 MB < 4 MiB L2) instead of the whole 8.5 MB
// canvas -> source pulled from L3 once per XCD per transform, not thrashed.
constexpr int W = 1024;
constexpr int H = 1024;
constexpr int T = 16;
constexpr int ITERS = 20;
constexpr int P2 = 1040;                 // f2 elements per row (8320 B rows)
constexpr int ROWS2 = 1027;              // rows 0..1026 readable
constexpr int ALLOC2F = ROWS2 * P2 * 2;  // floats per pair-buffer allocation
constexpr int TILES_X = W / 16;          // 64
constexpr int TILES_Y = H / 16;          // 64
constexpr int NTILES = TILES_X * TILES_Y;

typedef float f2 __attribute__((ext_vector_type(2), aligned(8)));
typedef float f4 __attribute__((ext_vector_type(4), aligned(8)));  // 8B-aligned ok

// coef per transform t: {p, Ax, Bx, Cxb, Ay, By, Cyb, 0}; Cxb/Cyb include the
// +1 pad shift AND +1 clamp bias.
__global__ void setup_coef(const float* __restrict__ theta,
                           const float* __restrict__ probs,
                           float* __restrict__ coef) {
    int t = threadIdx.x;
    if (t >= T) return;
    float sum = 0.f;
    for (int i = 0; i < T; ++i) sum += probs[i];
    float p = probs[t] / sum;
    const float* th = theta + 6 * t;
    float a = th[0], b = th[1], c = th[2];
    float d = th[3], e = th[4], f = th[5];
    float Cx = a * ((1.0f - (float)W) * 0.5f)
             + b * ((1.0f - (float)H) * 0.5f)
             + (c + 1.0f) * ((float)W * 0.5f) - 0.5f;
    float Cy = d * ((1.0f - (float)W) * 0.5f)
             + e * ((1.0f - (float)H) * 0.5f)
             + (f + 1.0f) * ((float)H * 0.5f) - 0.5f;
    float* o = coef + 8 * t;
    o[0] = p;  o[1] = a;  o[2] = b;  o[3] = Cx + 2.0f;
    o[4] = d;  o[5] = e;  o[6] = Cy + 2.0f; o[7] = 0.f;
}

// One thread per 16x16 tile: conservative bbox hit test (exact skip), compact
// the active transforms' 8-float coef rows, zero-pad count to multiple of 4
// (dummy rows are all-zero -> p=0, off=0 -> exact no-op).
__global__ __launch_bounds__(256) void setup_tiles(const float* __restrict__ coef,
                                                   float* __restrict__ tbl,
                                                   int* __restrict__ tcnt) {
    int tile = blockIdx.x * 256 + threadIdx.x;
    if (tile >= NTILES) return;
    int tx = tile & (TILES_X - 1), ty = tile >> 6;
    float w0 = (float)(tx * 16), w1 = w0 + 15.f;
    float h0 = (float)(ty * 16), h1 = h0 + 15.f;
    float* o = tbl + tile * 128;
    int n = 0;
    for (int t = 0; t < T; ++t) {
        const float* c = coef + t * 8;
        float Ax = c[1], Bx = c[2], Cx = c[3];
        float Ay = c[4], By = c[5], Cy = c[6];
        float xmin = Cx + (Ax >= 0.f ? Ax * w0 : Ax * w1) + (Bx >= 0.f ? Bx * h0 : Bx * h1);
        float xmax = Cx + (Ax >= 0.f ? Ax * w1 : Ax * w0) + (Bx >= 0.f ? Bx * h1 : Bx * h0);
        float ymin = Cy + (Ay >= 0.f ? Ay * w0 : Ay * w1) + (By >= 0.f ? By * h0 : By * h1);
        float ymax = Cy + (Ay >= 0.f ? Ay * w1 : Ay * w0) + (By >= 0.f ? By * h1 : By * h0);
        bool hit = !(xmax <= 1.f || xmin >= (float)(W + 2) ||
                     ymax <= 1.f || ymin >= (float)(H + 2));
        if (hit) {
            for (int j = 0; j < 8; ++j) o[n * 8 + j] = c[j];
            ++n;
        }
    }
    tcnt[tile] = n;
    int np = (n + 3) & ~3;
    for (int s = n; s < np; ++s)
        for (int j = 0; j < 8; ++j) o[s * 8 + j] = 0.f;
}

// Build initial pair buffer from canvas0: pixel (h,w) value v contributes
// buf2[h+2][w+2].x = v and buf2[h+1][w+2].y = v. Borders stay memset-zero.
__global__ __launch_bounds__(256) void copy_in(const float* __restrict__ src,
                                               float* __restrict__ dstf) {
    int i = blockIdx.x * 256 + threadIdx.x;   // i in [0, H*W)
    int h = i >> 10, w = i & 1023;
    float v = src[i];
    int c = w + 2;
    dstf[(((h + 2) * P2) + c) * 2 + 0] = v;
    dstf[(((h + 1) * P2) + c) * 2 + 1] = v;
}

// K transforms per group: coefs via uniform scalar loads; one f4 gather per
// transform fetches all 4 corners (v00,v10,v01,v11).
template <int K>
__device__ __forceinline__ void ifs_body(const float* __restrict__ tc, int g,
                                         const f2* __restrict__ gb,
                                         float wf, float hf, float& acc) {
    float fx[K], fy[K], pp[K];
    int off[K];
#pragma unroll
    for (int k = 0; k < K; ++k) {
        const float* c = tc + (g + k) * 8;          // uniform -> s_load
        float p = c[0], Ax = c[1], Bx = c[2], Cx = c[3];
        float Ay = c[4], By = c[5], Cy = c[6];
        float xb = fmaf(Ax, wf, fmaf(Bx, hf, Cx));
        float yb = fmaf(Ay, wf, fmaf(By, hf, Cy));
        float xc = fminf(fmaxf(xb, 0.f), 1037.f);   // v_med3
        float yc = fminf(fmaxf(yb, 0.f), 1026.f);
        float xi = floorf(xc), yi = floorf(yc);
        fx[k] = xc - xi;
        fy[k] = yc - yi;
        off[k] = (int)fmaf(yi, (float)P2, xi);      // exact (< 2^24)
        pp[k] = p;
    }
    f4 q[K];
#pragma unroll
    for (int k = 0; k < K; ++k)                     // K gathers in flight
        q[k] = *(const f4*)(gb + off[k]);
#pragma unroll
    for (int k = 0; k < K; ++k) {
        // q = (v00, v10, v01, v11)
        float top = fmaf(fx[k], q[k].z - q[k].x, q[k].x);
        float bot = fmaf(fx[k], q[k].w - q[k].y, q[k].y);
        acc = fmaf(pp[k], fmaf(fy[k], bot - top, top), acc);
    }
}

__global__ __launch_bounds__(256) void ifs_iter(const float* __restrict__ inf,
                                                float* __restrict__ dstf,
                                                const float* __restrict__ tbl,
                                                const int* __restrict__ tcnt,
                                                const float* __restrict__ base,
                                                int last) {
    // XCD-aware swizzle: 8 XCDs, 4096 blocks, round-robin dispatch assumed.
    // XCD k owns tiles [k*512, (k+1)*512) = a contiguous 128-row dst band.
    int lin = blockIdx.x;
    int tile = ((lin & 7) << 9) | (lin >> 3);       // bijective (4096 % 8 == 0)
    int tx = tile & (TILES_X - 1), ty = tile >> 6;

    const float* tc = tbl + tile * 128;             // uniform
    int np = (tcnt[tile] + 3) & ~3;                 // uniform trip count

    // 8x8-per-wave mapping; 4 waves tile a 16x16 pixel block.
    int lid = threadIdx.x;
    int lane = lid & 63, wv = lid >> 6;
    int w = (tx << 4) + ((wv & 1) << 3) + (lane & 7);
    int h = (ty << 4) + ((wv >> 1) << 3) + (lane >> 3);
    float wf = (float)w, hf = (float)h;
    const f2* gb = (const f2*)inf;

    float acc = 0.f;
    int g = 0;
    for (; g + 8 <= np; g += 8) ifs_body<8>(tc, g, gb, wf, hf, acc);
    if (g < np)                 ifs_body<4>(tc, g, gb, wf, hf, acc);

    if (last) {
        dstf[(h << 10) + w] = acc + base[0];
    } else {
        int c = w + 2;
        dstf[(((h + 2) * P2) + c) * 2 + 0] = acc;
        dstf[(((h + 1) * P2) + c) * 2 + 1] = acc;
    }
}

extern "C" void kernel_launch(void* const* d_in, const int* in_sizes, int n_in,
                              void* d_out, int out_size, void* d_ws, size_t ws_size,
                              hipStream_t stream) {
    const float* canvas0 = (const float*)d_in[0];
    const float* theta   = (const float*)d_in[1];
    const float* probs   = (const float*)d_in[2];
    const float* base    = (const float*)d_in[3];

    float* raw   = (float*)d_ws;
    float* bufAf = raw;
    float* bufBf = raw + ALLOC2F;
    float* coef  = raw + 2 * ALLOC2F;
    float* tbl   = coef + T * 8;
    int*   tcnt  = (int*)(tbl + NTILES * 128);

    // zero both pair buffers: borders, gutters, guards (and kills poison)
    hipMemsetAsync(raw, 0, (size_t)2 * ALLOC2F * sizeof(float), stream);

    setup_coef<<<1, 64, 0, stream>>>(theta, probs, coef);
    setup_tiles<<<(NTILES + 255) / 256, 256, 0, stream>>>(coef, tbl, tcnt);
    copy_in<<<(H * W) / 256, 256, 0, stream>>>(canvas0, bufAf);

    dim3 block(256);
    dim3 grid(NTILES);

    const float* cur = bufAf;
    for (int i = 0; i < ITERS; ++i) {
        bool last = (i == ITERS - 1);
        float* dst = last ? (float*)d_out : ((i & 1) ? bufAf : bufBf);
        ifs_iter<<<grid, block, 0, stream>>>(cur, dst, tbl, tcnt, base,
                                             last ? 1 : 0);
        cur = dst;
    }
}

// Round 5
// 387.237 us; speedup vs baseline: 1.0312x; 1.0312x over previous
//
#include <hip/hip_runtime.h>

// H=W=1024, T=16, 20 iterations.
//
// R10 = R8 (pair-buffer, single-f4-gather) + 512-thread blocks (32x16 tile,
// 8 waves) + per-group __syncthreads. Goal: the 2 co-resident blocks/CU keep
// their per-transform source bboxes (~2 x 7 KB) L1-resident while phase-
// aligned waves consume them -> gathers hit L1 instead of streaming from L2.
// XCD swizzle REVERTED (R9: -6%).
//
// Intermediates live in two VERTICAL-PAIR buffers:
//   buf2[r][c] = ( pad[r-1][c-1], pad[r][c-1] )   (float2, 8 B)
// where pad[y][x] is the zero-bordered padded canvas (pixel (h,w) at
// pad[h+1][w+1]). The 4 bilinear corners of a sample live in TWO ADJACENT f2
// elements -> ONE 16B dwordx4 gather per (pixel, transform). Guards/gutters
// are memset-zero once and never written, so clamped OOB samples read exact
// 0.0 (zeros padding exact, no per-lane cmp/cndmask).
constexpr int W = 1024;
constexpr int H = 1024;
constexpr int T = 16;
constexpr int ITERS = 20;
constexpr int P2 = 1040;                 // f2 elements per row (8320 B rows)
constexpr int ROWS2 = 1027;              // rows 0..1026 readable
constexpr int ALLOC2F = ROWS2 * P2 * 2;  // floats per pair-buffer allocation
constexpr int TILE_W = 32;
constexpr int TILE_H = 16;
constexpr int TILES_X = W / TILE_W;      // 32
constexpr int TILES_Y = H / TILE_H;      // 64
constexpr int NTILES = TILES_X * TILES_Y;  // 2048

typedef float f2 __attribute__((ext_vector_type(2), aligned(8)));
typedef float f4 __attribute__((ext_vector_type(4), aligned(8)));  // 8B-aligned ok

// coef per transform t: {p, Ax, Bx, Cxb, Ay, By, Cyb, 0}; Cxb/Cyb include the
// +1 pad shift AND +1 clamp bias.
__global__ void setup_coef(const float* __restrict__ theta,
                           const float* __restrict__ probs,
                           float* __restrict__ coef) {
    int t = threadIdx.x;
    if (t >= T) return;
    float sum = 0.f;
    for (int i = 0; i < T; ++i) sum += probs[i];
    float p = probs[t] / sum;
    const float* th = theta + 6 * t;
    float a = th[0], b = th[1], c = th[2];
    float d = th[3], e = th[4], f = th[5];
    float Cx = a * ((1.0f - (float)W) * 0.5f)
             + b * ((1.0f - (float)H) * 0.5f)
             + (c + 1.0f) * ((float)W * 0.5f) - 0.5f;
    float Cy = d * ((1.0f - (float)W) * 0.5f)
             + e * ((1.0f - (float)H) * 0.5f)
             + (f + 1.0f) * ((float)H * 0.5f) - 0.5f;
    float* o = coef + 8 * t;
    o[0] = p;  o[1] = a;  o[2] = b;  o[3] = Cx + 2.0f;
    o[4] = d;  o[5] = e;  o[6] = Cy + 2.0f; o[7] = 0.f;
}

// One thread per 32x16 tile: conservative bbox hit test (exact skip), compact
// the active transforms' 8-float coef rows, zero-pad count to multiple of 4
// (dummy rows are all-zero -> p=0, off=0 -> exact no-op).
__global__ __launch_bounds__(256) void setup_tiles(const float* __restrict__ coef,
                                                   float* __restrict__ tbl,
                                                   int* __restrict__ tcnt) {
    int tile = blockIdx.x * 256 + threadIdx.x;
    if (tile >= NTILES) return;
    int tx = tile & (TILES_X - 1), ty = tile / TILES_X;
    float w0 = (float)(tx * TILE_W), w1 = w0 + (float)(TILE_W - 1);
    float h0 = (float)(ty * TILE_H), h1 = h0 + (float)(TILE_H - 1);
    float* o = tbl + tile * 128;
    int n = 0;
    for (int t = 0; t < T; ++t) {
        const float* c = coef + t * 8;
        float Ax = c[1], Bx = c[2], Cx = c[3];
        float Ay = c[4], By = c[5], Cy = c[6];
        float xmin = Cx + (Ax >= 0.f ? Ax * w0 : Ax * w1) + (Bx >= 0.f ? Bx * h0 : Bx * h1);
        float xmax = Cx + (Ax >= 0.f ? Ax * w1 : Ax * w0) + (Bx >= 0.f ? Bx * h1 : Bx * h0);
        float ymin = Cy + (Ay >= 0.f ? Ay * w0 : Ay * w1) + (By >= 0.f ? By * h0 : By * h1);
        float ymax = Cy + (Ay >= 0.f ? Ay * w1 : Ay * w0) + (By >= 0.f ? By * h1 : By * h0);
        bool hit = !(xmax <= 1.f || xmin >= (float)(W + 2) ||
                     ymax <= 1.f || ymin >= (float)(H + 2));
        if (hit) {
            for (int j = 0; j < 8; ++j) o[n * 8 + j] = c[j];
            ++n;
        }
    }
    tcnt[tile] = n;
    int np = (n + 3) & ~3;
    for (int s = n; s < np; ++s)
        for (int j = 0; j < 8; ++j) o[s * 8 + j] = 0.f;
}

// Build initial pair buffer from canvas0: pixel (h,w) value v contributes
// buf2[h+2][w+2].x = v and buf2[h+1][w+2].y = v. Borders stay memset-zero.
__global__ __launch_bounds__(256) void copy_in(const float* __restrict__ src,
                                               float* __restrict__ dstf) {
    int i = blockIdx.x * 256 + threadIdx.x;   // i in [0, H*W)
    int h = i >> 10, w = i & 1023;
    float v = src[i];
    int c = w + 2;
    dstf[(((h + 2) * P2) + c) * 2 + 0] = v;
    dstf[(((h + 1) * P2) + c) * 2 + 1] = v;
}

// K transforms per group: coefs via uniform scalar loads; one f4 gather per
// transform fetches all 4 corners (v00,v10,v01,v11).
template <int K>
__device__ __forceinline__ void ifs_body(const float* __restrict__ tc, int g,
                                         const f2* __restrict__ gb,
                                         float wf, float hf, float& acc) {
    float fx[K], fy[K], pp[K];
    int off[K];
#pragma unroll
    for (int k = 0; k < K; ++k) {
        const float* c = tc + (g + k) * 8;          // uniform -> s_load
        float p = c[0], Ax = c[1], Bx = c[2], Cx = c[3];
        float Ay = c[4], By = c[5], Cy = c[6];
        float xb = fmaf(Ax, wf, fmaf(Bx, hf, Cx));
        float yb = fmaf(Ay, wf, fmaf(By, hf, Cy));
        float xc = fminf(fmaxf(xb, 0.f), 1037.f);   // v_med3
        float yc = fminf(fmaxf(yb, 0.f), 1026.f);
        float xi = floorf(xc), yi = floorf(yc);
        fx[k] = xc - xi;
        fy[k] = yc - yi;
        off[k] = (int)fmaf(yi, (float)P2, xi);      // exact (< 2^24)
        pp[k] = p;
    }
    f4 q[K];
#pragma unroll
    for (int k = 0; k < K; ++k)                     // K gathers in flight
        q[k] = *(const f4*)(gb + off[k]);
#pragma unroll
    for (int k = 0; k < K; ++k) {
        // q = (v00, v10, v01, v11)
        float top = fmaf(fx[k], q[k].z - q[k].x, q[k].x);
        float bot = fmaf(fx[k], q[k].w - q[k].y, q[k].y);
        acc = fmaf(pp[k], fmaf(fy[k], bot - top, top), acc);
    }
}

__global__ __launch_bounds__(512) void ifs_iter(const float* __restrict__ inf,
                                                float* __restrict__ dstf,
                                                const float* __restrict__ tbl,
                                                const int* __restrict__ tcnt,
                                                const float* __restrict__ base,
                                                int last) {
    int tile = blockIdx.y * TILES_X + blockIdx.x;
    const float* tc = tbl + tile * 128;             // uniform
    int np = (tcnt[tile] + 3) & ~3;                 // uniform trip count

    // 8x8-per-wave mapping; 8 waves (4x2) tile a 32x16 pixel block.
    int lid = threadIdx.x;
    int lane = lid & 63, wv = lid >> 6;             // wv in 0..7
    int w = (blockIdx.x << 5) + ((wv & 3) << 3) + (lane & 7);
    int h = (blockIdx.y << 4) + ((wv >> 2) << 3) + (lane >> 3);
    float wf = (float)w, hf = (float)h;
    const f2* gb = (const f2*)inf;

    float acc = 0.f;
    int g = 0;
    for (; g + 8 <= np; g += 8) {
        __syncthreads();                // phase-align the block's 8 waves
        ifs_body<8>(tc, g, gb, wf, hf, acc);
    }
    if (g < np) {
        __syncthreads();
        ifs_body<4>(tc, g, gb, wf, hf, acc);
    }

    if (last) {
        dstf[(h << 10) + w] = acc + base[0];
    } else {
        int c = w + 2;
        dstf[(((h + 2) * P2) + c) * 2 + 0] = acc;
        dstf[(((h + 1) * P2) + c) * 2 + 1] = acc;
    }
}

extern "C" void kernel_launch(void* const* d_in, const int* in_sizes, int n_in,
                              void* d_out, int out_size, void* d_ws, size_t ws_size,
                              hipStream_t stream) {
    const float* canvas0 = (const float*)d_in[0];
    const float* theta   = (const float*)d_in[1];
    const float* probs   = (const float*)d_in[2];
    const float* base    = (const float*)d_in[3];

    float* raw   = (float*)d_ws;
    float* bufAf = raw;
    float* bufBf = raw + ALLOC2F;
    float* coef  = raw + 2 * ALLOC2F;
    float* tbl   = coef + T * 8;
    int*   tcnt  = (int*)(tbl + NTILES * 128);

    // zero both pair buffers: borders, gutters, guards (and kills poison)
    hipMemsetAsync(raw, 0, (size_t)2 * ALLOC2F * sizeof(float), stream);

    setup_coef<<<1, 64, 0, stream>>>(theta, probs, coef);
    setup_tiles<<<(NTILES + 255) / 256, 256, 0, stream>>>(coef, tbl, tcnt);
    copy_in<<<(H * W) / 256, 256, 0, stream>>>(canvas0, bufAf);

    dim3 block(512);
    dim3 grid(TILES_X, TILES_Y);

    const float* cur = bufAf;
    for (int i = 0; i < ITERS; ++i) {
        bool last = (i == ITERS - 1);
        float* dst = last ? (float*)d_out : ((i & 1) ? bufAf : bufBf);
        ifs_iter<<<grid, block, 0, stream>>>(cur, dst, tbl, tcnt, base,
                                             last ? 1 : 0);
        cur = dst;
    }
}

// Round 6
// 374.329 us; speedup vs baseline: 1.0668x; 1.0345x over previous
//
#include <hip/hip_runtime.h>

// H=W=1024, T=16, 20 iterations.
//
// R11 = R8 (pair-buffer, single-f4-gather, 256-thr blocks, no syncs/swizzle)
//       + EXACT zero-contribution skipping:
//   - a sample contributes exactly 0 iff xb<=1 || xb>=1026 || yb<=1 || yb>=1026
//     (all 4 corners then lie in zero border/guard cells; fmaf(p,0,acc)==acc
//     bit-exactly, and acc is a sum of nonnegative products so never -0).
//   - wave-level: if no lane is live for transform k, skip its gather entirely
//     (scalar branch on __ballot).
//   - lane-level: dead lanes in live waves collapse their offset to 0 (guard
//     row, all-zero cells) -> one broadcast line instead of scattered rail
//     probes.
//
// Intermediates live in two VERTICAL-PAIR buffers:
//   buf2[r][c] = ( pad[r-1][c-1], pad[r][c-1] )   (float2, 8 B)
// where pad[y][x] is the zero-bordered padded canvas (pixel (h,w) at
// pad[h+1][w+1]). The 4 bilinear corners of a sample live in TWO ADJACENT f2
// elements -> ONE 16B dwordx4 gather per (pixel, transform). Guards/gutters
// are memset-zero once and never written, so clamped OOB samples read exact
// 0.0 (zeros padding exact, no per-lane cmp/cndmask in the value path).
constexpr int W = 1024;
constexpr int H = 1024;
constexpr int T = 16;
constexpr int ITERS = 20;
constexpr int P2 = 1040;                 // f2 elements per row (8320 B rows)
constexpr int ROWS2 = 1027;              // rows 0..1026 readable
constexpr int ALLOC2F = ROWS2 * P2 * 2;  // floats per pair-buffer allocation
constexpr int TILES_X = W / 16;          // 64
constexpr int TILES_Y = H / 16;          // 64
constexpr int NTILES = TILES_X * TILES_Y;

typedef float f2 __attribute__((ext_vector_type(2), aligned(8)));
typedef float f4 __attribute__((ext_vector_type(4), aligned(8)));  // 8B-aligned ok

// coef per transform t: {p, Ax, Bx, Cxb, Ay, By, Cyb, 0}; Cxb/Cyb include the
// +1 pad shift AND +1 clamp bias.
__global__ void setup_coef(const float* __restrict__ theta,
                           const float* __restrict__ probs,
                           float* __restrict__ coef) {
    int t = threadIdx.x;
    if (t >= T) return;
    float sum = 0.f;
    for (int i = 0; i < T; ++i) sum += probs[i];
    float p = probs[t] / sum;
    const float* th = theta + 6 * t;
    float a = th[0], b = th[1], c = th[2];
    float d = th[3], e = th[4], f = th[5];
    float Cx = a * ((1.0f - (float)W) * 0.5f)
             + b * ((1.0f - (float)H) * 0.5f)
             + (c + 1.0f) * ((float)W * 0.5f) - 0.5f;
    float Cy = d * ((1.0f - (float)W) * 0.5f)
             + e * ((1.0f - (float)H) * 0.5f)
             + (f + 1.0f) * ((float)H * 0.5f) - 0.5f;
    float* o = coef + 8 * t;
    o[0] = p;  o[1] = a;  o[2] = b;  o[3] = Cx + 2.0f;
    o[4] = d;  o[5] = e;  o[6] = Cy + 2.0f; o[7] = 0.f;
}

// One thread per 16x16 tile: conservative bbox hit test (exact skip), compact
// the active transforms' 8-float coef rows, zero-pad count to multiple of 4
// (dummy rows are all-zero -> p=0, off=0 -> exact no-op).
__global__ __launch_bounds__(256) void setup_tiles(const float* __restrict__ coef,
                                                   float* __restrict__ tbl,
                                                   int* __restrict__ tcnt) {
    int tile = blockIdx.x * 256 + threadIdx.x;
    if (tile >= NTILES) return;
    int tx = tile & (TILES_X - 1), ty = tile >> 6;
    float w0 = (float)(tx * 16), w1 = w0 + 15.f;
    float h0 = (float)(ty * 16), h1 = h0 + 15.f;
    float* o = tbl + tile * 128;
    int n = 0;
    for (int t = 0; t < T; ++t) {
        const float* c = coef + t * 8;
        float Ax = c[1], Bx = c[2], Cx = c[3];
        float Ay = c[4], By = c[5], Cy = c[6];
        float xmin = Cx + (Ax >= 0.f ? Ax * w0 : Ax * w1) + (Bx >= 0.f ? Bx * h0 : Bx * h1);
        float xmax = Cx + (Ax >= 0.f ? Ax * w1 : Ax * w0) + (Bx >= 0.f ? Bx * h1 : Bx * h0);
        float ymin = Cy + (Ay >= 0.f ? Ay * w0 : Ay * w1) + (By >= 0.f ? By * h0 : By * h1);
        float ymax = Cy + (Ay >= 0.f ? Ay * w1 : Ay * w0) + (By >= 0.f ? By * h1 : By * h0);
        bool hit = !(xmax <= 1.f || xmin >= (float)(W + 2) ||
                     ymax <= 1.f || ymin >= (float)(H + 2));
        if (hit) {
            for (int j = 0; j < 8; ++j) o[n * 8 + j] = c[j];
            ++n;
        }
    }
    tcnt[tile] = n;
    int np = (n + 3) & ~3;
    for (int s = n; s < np; ++s)
        for (int j = 0; j < 8; ++j) o[s * 8 + j] = 0.f;
}

// Build initial pair buffer from canvas0: pixel (h,w) value v contributes
// buf2[h+2][w+2].x = v and buf2[h+1][w+2].y = v. Borders stay memset-zero.
__global__ __launch_bounds__(256) void copy_in(const float* __restrict__ src,
                                               float* __restrict__ dstf) {
    int i = blockIdx.x * 256 + threadIdx.x;   // i in [0, H*W)
    int h = i >> 10, w = i & 1023;
    float v = src[i];
    int c = w + 2;
    dstf[(((h + 2) * P2) + c) * 2 + 0] = v;
    dstf[(((h + 1) * P2) + c) * 2 + 1] = v;
}

// K transforms per group: coefs via uniform scalar loads; one f4 gather per
// transform fetches all 4 corners (v00,v10,v01,v11). Fully-dead wave skips
// the gather (scalar branch); dead lanes collapse to offset 0.
template <int K>
__device__ __forceinline__ void ifs_body(const float* __restrict__ tc, int g,
                                         const f2* __restrict__ gb,
                                         float wf, float hf, float& acc) {
    float fx[K], fy[K], pp[K];
    int off[K];
    unsigned long long lv[K];
#pragma unroll
    for (int k = 0; k < K; ++k) {
        const float* c = tc + (g + k) * 8;          // uniform -> s_load
        float p = c[0], Ax = c[1], Bx = c[2], Cx = c[3];
        float Ay = c[4], By = c[5], Cy = c[6];
        float xb = fmaf(Ax, wf, fmaf(Bx, hf, Cx));
        float yb = fmaf(Ay, wf, fmaf(By, hf, Cy));
        // live <=> contribution can be nonzero
        bool live = (xb > 1.f) & (xb < 1026.f) & (yb > 1.f) & (yb < 1026.f);
        lv[k] = __ballot(live);
        float xc = fminf(fmaxf(xb, 0.f), 1037.f);   // v_med3
        float yc = fminf(fmaxf(yb, 0.f), 1026.f);
        float xi = floorf(xc), yi = floorf(yc);
        fx[k] = xc - xi;
        fy[k] = yc - yi;
        int o = (int)fmaf(yi, (float)P2, xi);       // exact (< 2^24)
        off[k] = live ? o : 0;                      // dead lane -> guard row 0
        pp[k] = p;
    }
    f4 q[K];
#pragma unroll
    for (int k = 0; k < K; ++k) {                   // live gathers in flight
        if (lv[k]) q[k] = *(const f4*)(gb + off[k]);
        else       q[k] = f4{0.f, 0.f, 0.f, 0.f};   // all corners zero
    }
#pragma unroll
    for (int k = 0; k < K; ++k) {
        // q = (v00, v10, v01, v11)
        float top = fmaf(fx[k], q[k].z - q[k].x, q[k].x);
        float bot = fmaf(fx[k], q[k].w - q[k].y, q[k].y);
        acc = fmaf(pp[k], fmaf(fy[k], bot - top, top), acc);
    }
}

__global__ __launch_bounds__(256) void ifs_iter(const float* __restrict__ inf,
                                                float* __restrict__ dstf,
                                                const float* __restrict__ tbl,
                                                const int* __restrict__ tcnt,
                                                const float* __restrict__ base,
                                                int last) {
    int tile = blockIdx.y * TILES_X + blockIdx.x;
    const float* tc = tbl + tile * 128;             // uniform
    int np = (tcnt[tile] + 3) & ~3;                 // uniform trip count

    // 8x8-per-wave mapping; 4 waves tile a 16x16 pixel block.
    int lid = threadIdx.x;
    int lane = lid & 63, wv = lid >> 6;
    int w = (blockIdx.x << 4) + ((wv & 1) << 3) + (lane & 7);
    int h = (blockIdx.y << 4) + ((wv >> 1) << 3) + (lane >> 3);
    float wf = (float)w, hf = (float)h;
    const f2* gb = (const f2*)inf;

    float acc = 0.f;
    int g = 0;
    for (; g + 8 <= np; g += 8) ifs_body<8>(tc, g, gb, wf, hf, acc);
    if (g < np)                 ifs_body<4>(tc, g, gb, wf, hf, acc);

    if (last) {
        dstf[(h << 10) + w] = acc + base[0];
    } else {
        int c = w + 2;
        dstf[(((h + 2) * P2) + c) * 2 + 0] = acc;
        dstf[(((h + 1) * P2) + c) * 2 + 1] = acc;
    }
}

extern "C" void kernel_launch(void* const* d_in, const int* in_sizes, int n_in,
                              void* d_out, int out_size, void* d_ws, size_t ws_size,
                              hipStream_t stream) {
    const float* canvas0 = (const float*)d_in[0];
    const float* theta   = (const float*)d_in[1];
    const float* probs   = (const float*)d_in[2];
    const float* base    = (const float*)d_in[3];

    float* raw   = (float*)d_ws;
    float* bufAf = raw;
    float* bufBf = raw + ALLOC2F;
    float* coef  = raw + 2 * ALLOC2F;
    float* tbl   = coef + T * 8;
    int*   tcnt  = (int*)(tbl + NTILES * 128);

    // zero both pair buffers: borders, gutters, guards (and kills poison)
    hipMemsetAsync(raw, 0, (size_t)2 * ALLOC2F * sizeof(float), stream);

    setup_coef<<<1, 64, 0, stream>>>(theta, probs, coef);
    setup_tiles<<<(NTILES + 255) / 256, 256, 0, stream>>>(coef, tbl, tcnt);
    copy_in<<<(H * W) / 256, 256, 0, stream>>>(canvas0, bufAf);

    dim3 block(256);
    dim3 grid(TILES_X, TILES_Y);

    const float* cur = bufAf;
    for (int i = 0; i < ITERS; ++i) {
        bool last = (i == ITERS - 1);
        float* dst = last ? (float*)d_out : ((i & 1) ? bufAf : bufBf);
        ifs_iter<<<grid, block, 0, stream>>>(cur, dst, tbl, tcnt, base,
                                             last ? 1 : 0);
        cur = dst;
    }
}